// Round 1
// baseline (464.423 us; speedup 1.0000x reference)
//
#include <hip/hip_runtime.h>

#define EPB     128          // edges per block
#define E_TOTAL 262144
#define NPROBE  100000

#define HSTR 392             // H row stride (shorts): 784 B = 16 B * 49 (odd) -> conflict-friendly
#define ASTR 136             // A2/F1A/GA row stride: 272 B = 16 B * 17
#define WSTR 136             // WBUF row stride
#define ESTR 40              // EPI row stride: 80 B = 16 B * 5
#define F1OFF 17408          // F1A offset (shorts) inside Hs region

typedef __attribute__((ext_vector_type(8))) short  short8;
typedef __attribute__((ext_vector_type(4))) float  floatx4;

#define MFMA16(a, b, c) __builtin_amdgcn_mfma_f32_16x16x32_bf16((a), (b), (c), 0, 0, 0)

__device__ __forceinline__ short f2bf(float x) {
    unsigned u = __builtin_bit_cast(unsigned, x);
    u = (u + 0x7FFFu + ((u >> 16) & 1u)) >> 16;   // RNE
    return (short)(unsigned short)u;
}

__device__ __forceinline__ float silu_f(float x) { return x / (1.0f + __expf(-x)); }

struct F8 { float v[8]; };
__device__ __forceinline__ F8 ld8(const float* __restrict__ p) {
    F8 r;
    const float4 a = *(const float4*)p;
    const float4 b = *(const float4*)(p + 4);
    r.v[0] = a.x; r.v[1] = a.y; r.v[2] = a.z; r.v[3] = a.w;
    r.v[4] = b.x; r.v[5] = b.y; r.v[6] = b.z; r.v[7] = b.w;
    return r;
}

// Stage a KxN fp32 weight block into LDS as bf16, transposed to [n][k] so
// B-fragments are 16 B-contiguous. WB[n*WSTR + kk] = bf16(Wg[(kbase+kk)*ldn + n]).
__device__ __forceinline__ void stage_w(const float* __restrict__ Wg, int ldn,
                                        int kbase, int nrows, int kcnt,
                                        unsigned short* __restrict__ WB, int t) {
    const int items = nrows * (kcnt >> 3);
    for (int idx = t; idx < items; idx += 256) {
        int n  = idx & (nrows - 1);        // nrows is a power of two (64 / 128)
        int kg = idx / nrows;
        int kk = kg << 3;
        short8 w;
#pragma unroll
        for (int j = 0; j < 8; ++j)
            w[j] = f2bf(Wg[(kbase + kk + j) * ldn + n]);   // coalesced: lanes sweep n
        *(short8*)&WB[n * WSTR + kk] = w;
    }
}

__global__ void cfr_init_out(float* __restrict__ out, const float* __restrict__ fb) {
    int i = blockIdx.x * 256 + threadIdx.x;
    if (i < NPROBE) out[i] = fb[0];
}

__global__ __launch_bounds__(256, 1) void cfr_main(
    const float* __restrict__ diff,  const float* __restrict__ S_JK,
    const float* __restrict__ V_JK,  const int* __restrict__ atom_idx,
    const int* __restrict__ probe_idx,
    const float* __restrict__ w_s1, const float* __restrict__ b_s1,
    const float* __restrict__ g_ln, const float* __restrict__ b_ln,
    const float* __restrict__ w_s2, const float* __restrict__ b_s2,
    const float* __restrict__ w_f1, const float* __restrict__ b_f1,
    const float* __restrict__ w_f2, const float* __restrict__ b_f2,
    const float* __restrict__ w_o1, const float* __restrict__ b_o1,
    const float* __restrict__ w_o2, const float* __restrict__ b_o2,
    float* __restrict__ out)
{
    // ~149 KB LDS total -> 1 block/CU on gfx950 (160 KB/WG)
    __shared__ __align__(16) unsigned short Hs[EPB * HSTR];     // 100352 B; later A2 @0, F1A @F1OFF, GA @0
    __shared__ __align__(16) unsigned short EPIs[EPB * ESTR];   // 10240 B
    __shared__ __align__(16) unsigned short WBUFs[128 * WSTR];  // 34816 B
    __shared__ float rdat[EPB][4];     // rx, ry, rz, dist
    __shared__ float invd_s[EPB];
    __shared__ float env_s[EPB];
    __shared__ int   probe_s[EPB];
    __shared__ int   atom_s[EPB];
    __shared__ float lnp[EPB][2][2];   // per-row (sum, sumsq) per col-half
    __shared__ float mpart[EPB][2];

    const int t    = threadIdx.x;
    const int e0   = blockIdx.x * EPB;
    const int wave = t >> 6;
    const int lane = t & 63;
    const int q    = lane >> 4;        // MFMA quad
    const int c16  = lane & 15;        // MFMA row/col-within-tile
    const int wm   = wave & 1;         // wave row-half
    const int wn   = wave >> 1;        // wave col-half
    const int rowb = wm * 64;
    const int colb = wn * 64;

    // ---------- phase 0: per-edge scalars ----------
    if (t < EPB) {
        int e = e0 + t;
        float dx = diff[e * 3 + 0], dy = diff[e * 3 + 1], dz = diff[e * 3 + 2];
        float sq   = dx * dx + dy * dy + dz * dz;
        float dist = sqrtf(sq);
        float rinv = 1.0f / sqrtf(sq + 1e-8f);     // r_hat uses dist_safe
        rdat[t][0] = dx * rinv; rdat[t][1] = dy * rinv; rdat[t][2] = dz * rinv;
        rdat[t][3] = dist;
        invd_s[t]  = 1.0f / dist;                  // e_pi uses exact dist
        float x  = dist * 0.25f;
        float x2 = x * x, x4 = x2 * x2;
        float x5 = x4 * x, x6 = x5 * x, x7 = x6 * x;
        float env = 1.0f - 21.0f * x5 + 35.0f * x6 - 15.0f * x7;
        env_s[t]  = (dist < 4.0f) ? env : 0.0f;
        probe_s[t] = probe_idx[e];
        atom_s[t]  = atom_idx[e];
    }
    __syncthreads();

    // ---------- phase 1a: sinc RBF -> EPIs (bf16, MFMA-A layout [e][n]) ----------
#pragma unroll
    for (int it = 0; it < 2; ++it) {
        int idx = it * 256 + t;
        int e = idx >> 2, ng = idx & 3;
        float dist = rdat[e][3];
        float inv  = invd_s[e];
        short8 pk;
#pragma unroll
        for (int j = 0; j < 8; ++j) {
            float nf = (float)(ng * 8 + j + 1);
            pk[j] = f2bf(__sinf(dist * nf * 0.785398163397448f) * inv);
        }
        *(short8*)&EPIs[e * ESTR + ng * 8] = pk;
    }

    // ---------- phase 1b: gather -> H = [S_e | n_e | q_pi] (bf16) ----------
#pragma unroll
    for (int it = 0; it < 8; ++it) {
        int idx = it * 256 + t;
        int e = idx >> 4, f = (idx & 15) * 8;
        int a = atom_s[e];
        F8 se = ld8(S_JK + a * 128 + f);
        F8 v0 = ld8(V_JK + a * 384 + f);
        F8 v1 = ld8(V_JK + a * 384 + 128 + f);
        F8 v2 = ld8(V_JK + a * 384 + 256 + f);
        float rx = rdat[e][0], ry = rdat[e][1], rz = rdat[e][2];
        short8 hS, hN, hQ;
#pragma unroll
        for (int j = 0; j < 8; ++j) {
            hS[j] = f2bf(se.v[j]);
            hN[j] = f2bf(sqrtf(v0.v[j] * v0.v[j] + v1.v[j] * v1.v[j] + v2.v[j] * v2.v[j] + 1e-8f));
            hQ[j] = f2bf(v0.v[j] * rx + v1.v[j] * ry + v2.v[j] * rz);
        }
        unsigned short* hr = &Hs[e * HSTR];
        *(short8*)&hr[f]       = hS;
        *(short8*)&hr[128 + f] = hN;
        *(short8*)&hr[256 + f] = hQ;
    }
    __syncthreads();

    // ---------- matmul 1: U[128x128] = H[128x384] @ w_s1 ----------
    floatx4 acc[4][4];
    const floatx4 zero4 = {0.f, 0.f, 0.f, 0.f};
#pragma unroll
    for (int mi = 0; mi < 4; ++mi)
#pragma unroll
        for (int ni = 0; ni < 4; ++ni) acc[mi][ni] = zero4;

    for (int c = 0; c < 3; ++c) {                       // K chunks of 128
        stage_w(w_s1, 128, c * 128, 128, 128, WBUFs, t);
        __syncthreads();
#pragma unroll
        for (int ks = 0; ks < 4; ++ks) {
            short8 af[4], bfr[4];
#pragma unroll
            for (int mi = 0; mi < 4; ++mi)
                af[mi] = *(const short8*)&Hs[(rowb + mi * 16 + c16) * HSTR + c * 128 + ks * 32 + q * 8];
#pragma unroll
            for (int ni = 0; ni < 4; ++ni)
                bfr[ni] = *(const short8*)&WBUFs[(colb + ni * 16 + c16) * WSTR + ks * 32 + q * 8];
#pragma unroll
            for (int mi = 0; mi < 4; ++mi)
#pragma unroll
                for (int ni = 0; ni < 4; ++ni)
                    acc[mi][ni] = MFMA16(af[mi], bfr[ni], acc[mi][ni]);
        }
        __syncthreads();
    }

    // ---------- LayerNorm over features, SiLU, write A2 (bf16) ----------
    float bs1c[4], glc[4], blc[4];
#pragma unroll
    for (int ni = 0; ni < 4; ++ni) {
        int col = colb + ni * 16 + c16;
        bs1c[ni] = b_s1[col]; glc[ni] = g_ln[col]; blc[ni] = b_ln[col];
    }
#pragma unroll
    for (int mi = 0; mi < 4; ++mi)
#pragma unroll
        for (int r = 0; r < 4; ++r) {
            float s = 0.f, s2 = 0.f;
#pragma unroll
            for (int ni = 0; ni < 4; ++ni) {
                float v = acc[mi][ni][r] + bs1c[ni];
                s += v; s2 += v * v;
            }
#pragma unroll
            for (int d = 1; d < 16; d <<= 1) {
                s  += __shfl_xor(s, d, 64);
                s2 += __shfl_xor(s2, d, 64);
            }
            if (c16 == 0) {
                int row = rowb + mi * 16 + q * 4 + r;
                lnp[row][wn][0] = s; lnp[row][wn][1] = s2;
            }
        }
    __syncthreads();
#pragma unroll
    for (int mi = 0; mi < 4; ++mi)
#pragma unroll
        for (int r = 0; r < 4; ++r) {
            int row = rowb + mi * 16 + q * 4 + r;
            float mu = (lnp[row][0][0] + lnp[row][1][0]) * (1.f / 128.f);
            float ms = (lnp[row][0][1] + lnp[row][1][1]) * (1.f / 128.f);
            float rstd = rsqrtf(ms - mu * mu + 1e-5f);
#pragma unroll
            for (int ni = 0; ni < 4; ++ni) {
                float v = acc[mi][ni][r] + bs1c[ni];
                float y = (v - mu) * rstd * glc[ni] + blc[ni];
                Hs[row * ASTR + (colb + ni * 16 + c16)] = (unsigned short)f2bf(silu_f(y));  // A2
            }
        }

    // ---------- filter matmul 1: F1[128x128] = EPI[128x32] @ w_f1 ----------
    stage_w(w_f1, 128, 0, 128, 32, WBUFs, t);
    __syncthreads();                                    // A2 + wf1 ready
    {
        short8 ae[4], be[4];
#pragma unroll
        for (int mi = 0; mi < 4; ++mi)
            ae[mi] = *(const short8*)&EPIs[(rowb + mi * 16 + c16) * ESTR + q * 8];
#pragma unroll
        for (int ni = 0; ni < 4; ++ni)
            be[ni] = *(const short8*)&WBUFs[(colb + ni * 16 + c16) * WSTR + q * 8];
#pragma unroll
        for (int mi = 0; mi < 4; ++mi)
#pragma unroll
            for (int ni = 0; ni < 4; ++ni)
                acc[mi][ni] = MFMA16(ae[mi], be[ni], zero4);   // reuse acc as F1
    }
    {
        float bf1c[4];
#pragma unroll
        for (int ni = 0; ni < 4; ++ni) bf1c[ni] = b_f1[colb + ni * 16 + c16];
#pragma unroll
        for (int mi = 0; mi < 4; ++mi)
#pragma unroll
            for (int r = 0; r < 4; ++r) {
                int row = rowb + mi * 16 + q * 4 + r;
#pragma unroll
                for (int ni = 0; ni < 4; ++ni) {
                    float v = acc[mi][ni][r] + bf1c[ni];
                    Hs[F1OFF + row * ASTR + (colb + ni * 16 + c16)] = (unsigned short)f2bf(silu_f(v));
                }
            }
    }
    __syncthreads();

    // ---------- matmul 2: S = A2 @ w_s2 ----------
    floatx4 sacc[4][4];
#pragma unroll
    for (int mi = 0; mi < 4; ++mi)
#pragma unroll
        for (int ni = 0; ni < 4; ++ni) sacc[mi][ni] = zero4;
    stage_w(w_s2, 128, 0, 128, 128, WBUFs, t);
    __syncthreads();
#pragma unroll
    for (int ks = 0; ks < 4; ++ks) {
        short8 af[4], bfr[4];
#pragma unroll
        for (int mi = 0; mi < 4; ++mi)
            af[mi] = *(const short8*)&Hs[(rowb + mi * 16 + c16) * ASTR + ks * 32 + q * 8];
#pragma unroll
        for (int ni = 0; ni < 4; ++ni)
            bfr[ni] = *(const short8*)&WBUFs[(colb + ni * 16 + c16) * WSTR + ks * 32 + q * 8];
#pragma unroll
        for (int mi = 0; mi < 4; ++mi)
#pragma unroll
            for (int ni = 0; ni < 4; ++ni)
                sacc[mi][ni] = MFMA16(af[mi], bfr[ni], sacc[mi][ni]);
    }
    __syncthreads();

    // ---------- filter matmul 2: W = F1A @ w_f2; G = W ⊙ S -> GA ----------
    stage_w(w_f2, 128, 0, 128, 128, WBUFs, t);
    __syncthreads();
    {
        floatx4 wacc[4][4];
#pragma unroll
        for (int mi = 0; mi < 4; ++mi)
#pragma unroll
            for (int ni = 0; ni < 4; ++ni) wacc[mi][ni] = zero4;
#pragma unroll
        for (int ks = 0; ks < 4; ++ks) {
            short8 af[4], bfr[4];
#pragma unroll
            for (int mi = 0; mi < 4; ++mi)
                af[mi] = *(const short8*)&Hs[F1OFF + (rowb + mi * 16 + c16) * ASTR + ks * 32 + q * 8];
#pragma unroll
            for (int ni = 0; ni < 4; ++ni)
                bfr[ni] = *(const short8*)&WBUFs[(colb + ni * 16 + c16) * WSTR + ks * 32 + q * 8];
#pragma unroll
            for (int mi = 0; mi < 4; ++mi)
#pragma unroll
                for (int ni = 0; ni < 4; ++ni)
                    wacc[mi][ni] = MFMA16(af[mi], bfr[ni], wacc[mi][ni]);
        }
        float bs2c[4], bf2c[4];
#pragma unroll
        for (int ni = 0; ni < 4; ++ni) {
            int col = colb + ni * 16 + c16;
            bs2c[ni] = b_s2[col]; bf2c[ni] = b_f2[col];
        }
#pragma unroll
        for (int mi = 0; mi < 4; ++mi)
#pragma unroll
            for (int r = 0; r < 4; ++r) {
                int row = rowb + mi * 16 + q * 4 + r;
#pragma unroll
                for (int ni = 0; ni < 4; ++ni) {
                    float g = (sacc[mi][ni][r] + bs2c[ni]) * (wacc[mi][ni][r] + bf2c[ni]);
                    Hs[row * ASTR + (colb + ni * 16 + c16)] = (unsigned short)f2bf(g);  // GA over A2
                }
            }
    }
    __syncthreads();

    // ---------- output head: O1[128x64] = GA @ w_o1; m = silu(O1) @ w_o2 ----------
    stage_w(w_o1, 64, 0, 64, 128, WBUFs, t);
    __syncthreads();
    {
        floatx4 oacc[4][2];
#pragma unroll
        for (int mi = 0; mi < 4; ++mi)
#pragma unroll
            for (int ni = 0; ni < 2; ++ni) oacc[mi][ni] = zero4;
#pragma unroll
        for (int ks = 0; ks < 4; ++ks) {
            short8 af[4], bfr[2];
#pragma unroll
            for (int mi = 0; mi < 4; ++mi)
                af[mi] = *(const short8*)&Hs[(rowb + mi * 16 + c16) * ASTR + ks * 32 + q * 8];
#pragma unroll
            for (int ni = 0; ni < 2; ++ni)
                bfr[ni] = *(const short8*)&WBUFs[(wn * 32 + ni * 16 + c16) * WSTR + ks * 32 + q * 8];
#pragma unroll
            for (int mi = 0; mi < 4; ++mi)
#pragma unroll
                for (int ni = 0; ni < 2; ++ni)
                    oacc[mi][ni] = MFMA16(af[mi], bfr[ni], oacc[mi][ni]);
        }
        float bo1c[2], wo2c[2];
#pragma unroll
        for (int ni = 0; ni < 2; ++ni) {
            int col = wn * 32 + ni * 16 + c16;
            bo1c[ni] = b_o1[col]; wo2c[ni] = w_o2[col];
        }
#pragma unroll
        for (int mi = 0; mi < 4; ++mi)
#pragma unroll
            for (int r = 0; r < 4; ++r) {
                float s = 0.f;
#pragma unroll
                for (int ni = 0; ni < 2; ++ni) {
                    float v = oacc[mi][ni][r] + bo1c[ni];
                    s += silu_f(v) * wo2c[ni];
                }
#pragma unroll
                for (int d = 1; d < 16; d <<= 1) s += __shfl_xor(s, d, 64);
                if (c16 == 0) mpart[rowb + mi * 16 + q * 4 + r][wn] = s;
            }
    }
    __syncthreads();

    // ---------- envelope + scatter-add ----------
    if (t < EPB) {
        float m  = mpart[t][0] + mpart[t][1] + b_o2[0];
        float mw = m * env_s[t];
        if (mw != 0.f) unsafeAtomicAdd(&out[probe_s[t]], mw);
    }
}

extern "C" void kernel_launch(void* const* d_in, const int* in_sizes, int n_in,
                              void* d_out, int out_size, void* d_ws, size_t ws_size,
                              hipStream_t stream) {
    const float* diff    = (const float*)d_in[0];
    const float* S_JK    = (const float*)d_in[1];
    const float* V_JK    = (const float*)d_in[2];
    const int*   atom_i  = (const int*)d_in[3];
    const int*   probe_i = (const int*)d_in[4];
    const float* w_s1 = (const float*)d_in[6];
    const float* b_s1 = (const float*)d_in[7];
    const float* g_ln = (const float*)d_in[8];
    const float* b_ln = (const float*)d_in[9];
    const float* w_s2 = (const float*)d_in[10];
    const float* b_s2 = (const float*)d_in[11];
    const float* w_f1 = (const float*)d_in[12];
    const float* b_f1 = (const float*)d_in[13];
    const float* w_f2 = (const float*)d_in[14];
    const float* b_f2 = (const float*)d_in[15];
    const float* w_o1 = (const float*)d_in[16];
    const float* b_o1 = (const float*)d_in[17];
    const float* w_o2 = (const float*)d_in[18];
    const float* b_o2 = (const float*)d_in[19];
    const float* fbias = (const float*)d_in[20];
    float* out = (float*)d_out;

    cfr_init_out<<<(NPROBE + 255) / 256, 256, 0, stream>>>(out, fbias);
    cfr_main<<<E_TOTAL / EPB, 256, 0, stream>>>(diff, S_JK, V_JK, atom_i, probe_i,
        w_s1, b_s1, g_ln, b_ln, w_s2, b_s2, w_f1, b_f1, w_f2, b_f2,
        w_o1, b_o1, w_o2, b_o2, out);
}

// Round 2
// 288.319 us; speedup vs baseline: 1.6108x; 1.6108x over previous
//
#include <hip/hip_runtime.h>

#define EPB     64           // edges per block
#define E_TOTAL 262144
#define NPROBE  100000

// LDS layout (unsigned short indices into LDSu; total 50,176 B + 2 KB misc)
#define HSTR   392           // H row stride (shorts): 784 B = 16 B * 49 -> 2-way (free) bank pattern
#define ASTR   136           // A2/F1A/GA row stride: 272 B = 16 B * 17
#define A2_O   0             // A2/GA region  [0, 8704) shorts
#define F1_O   8704          // F1A region    [8704, 17408)
#define EPI_O  17408         // EPI region    [17408, 19968), row stride 40 shorts
#define LNP_B  19968         // lnp  floats at short-idx 19968 (byte 39936), 64*4*2 floats
#define MPT_B  20992         // mpart floats at short-idx 20992 (byte 41984), 64*4 floats
#define LDS_SH 25088         // 64*392 shorts = 50,176 B

// bf16-transposed weight workspace offsets (shorts), layout WT[n][k] k-contiguous
#define WS1_O  0             // 128 x 384
#define WS2_O  49152         // 128 x 128
#define WF1_O  65536         // 128 x 32
#define WF2_O  69632         // 128 x 128
#define WO1_O  86016         // 64 x 128
#define WT_TOT 94208

typedef __attribute__((ext_vector_type(8))) short  short8;
typedef __attribute__((ext_vector_type(4))) float  floatx4;

#define MFMA16(a, b, c) __builtin_amdgcn_mfma_f32_16x16x32_bf16((a), (b), (c), 0, 0, 0)

__device__ __forceinline__ short f2bf(float x) {
    unsigned u = __builtin_bit_cast(unsigned, x);
    u = (u + 0x7FFFu + ((u >> 16) & 1u)) >> 16;   // RNE
    return (short)(unsigned short)u;
}

__device__ __forceinline__ float silu_f(float x) { return x / (1.0f + __expf(-x)); }

struct F8 { float v[8]; };
__device__ __forceinline__ F8 ld8(const float* __restrict__ p) {
    F8 r;
    const float4 a = *(const float4*)p;
    const float4 b = *(const float4*)(p + 4);
    r.v[0] = a.x; r.v[1] = a.y; r.v[2] = a.z; r.v[3] = a.w;
    r.v[4] = b.x; r.v[5] = b.y; r.v[6] = b.z; r.v[7] = b.w;
    return r;
}

// Once per launch: init out = final_bias, and convert all weights to
// bf16 transposed [n][k] (k-contiguous) so MFMA B-fragments are direct
// 16 B global loads (same address across blocks -> L2-broadcast-hot).
__global__ void cfr_prep(const float* __restrict__ w_s1, const float* __restrict__ w_s2,
                         const float* __restrict__ w_f1, const float* __restrict__ w_f2,
                         const float* __restrict__ w_o1,
                         const float* __restrict__ fb, float* __restrict__ out,
                         unsigned short* __restrict__ wt) {
    int i = blockIdx.x * 256 + threadIdx.x;
    if (i < NPROBE) out[i] = fb[0];
    if (i < WT_TOT) {
        float v;
        if (i < WS2_O)      { int n = i / 384, k = i - n * 384;        v = w_s1[k * 128 + n]; }
        else if (i < WF1_O) { int j = i - WS2_O, n = j >> 7, k = j & 127; v = w_s2[k * 128 + n]; }
        else if (i < WF2_O) { int j = i - WF1_O, n = j >> 5, k = j & 31;  v = w_f1[k * 128 + n]; }
        else if (i < WO1_O) { int j = i - WF2_O, n = j >> 7, k = j & 127; v = w_f2[k * 128 + n]; }
        else                { int j = i - WO1_O, n = j >> 7, k = j & 127; v = w_o1[k * 64 + n]; }
        wt[i] = (unsigned short)f2bf(v);
    }
}

__global__ __launch_bounds__(256, 3) void cfr_main(
    const float* __restrict__ diff,  const float* __restrict__ S_JK,
    const float* __restrict__ V_JK,  const int* __restrict__ atom_idx,
    const int* __restrict__ probe_idx,
    const unsigned short* __restrict__ wt,
    const float* __restrict__ b_s1, const float* __restrict__ g_ln,
    const float* __restrict__ b_ln, const float* __restrict__ b_s2,
    const float* __restrict__ b_f1, const float* __restrict__ b_f2,
    const float* __restrict__ b_o1, const float* __restrict__ w_o2,
    const float* __restrict__ b_o2,
    float* __restrict__ out)
{
    __shared__ __align__(16) unsigned short LDSu[LDS_SH];   // H, then A2/F1A/EPI/lnp/mpart overlays
    __shared__ float rdat[EPB][4];     // rx, ry, rz, dist
    __shared__ float invd_s[EPB];
    __shared__ float env_s[EPB];
    __shared__ int   probe_s[EPB];
    __shared__ int   atom_s[EPB];

    float* lnp   = (float*)&LDSu[LNP_B];   // [row][wave][2]
    float* mpart = (float*)&LDSu[MPT_B];   // [row][wave]

    const int t    = threadIdx.x;
    const int e0   = blockIdx.x * EPB;
    const int wave = t >> 6;
    const int lane = t & 63;
    const int q    = lane >> 4;        // MFMA quad
    const int c16  = lane & 15;

    // ---------- phase 0: per-edge scalars ----------
    if (t < EPB) {
        int e = e0 + t;
        float dx = diff[e * 3 + 0], dy = diff[e * 3 + 1], dz = diff[e * 3 + 2];
        float sq   = dx * dx + dy * dy + dz * dz;
        float dist = sqrtf(sq);
        float rinv = 1.0f / sqrtf(sq + 1e-8f);
        rdat[t][0] = dx * rinv; rdat[t][1] = dy * rinv; rdat[t][2] = dz * rinv;
        rdat[t][3] = dist;
        invd_s[t]  = 1.0f / dist;
        float x  = dist * 0.25f;
        float x2 = x * x, x4 = x2 * x2;
        float x5 = x4 * x, x6 = x5 * x, x7 = x6 * x;
        float env = 1.0f - 21.0f * x5 + 35.0f * x6 - 15.0f * x7;
        env_s[t]  = (dist < 4.0f) ? env : 0.0f;
        probe_s[t] = probe_idx[e];
        atom_s[t]  = atom_idx[e];
    }
    __syncthreads();

    // ---------- gather -> H = [S_e | n_e | q_pi] (bf16, rows 0..63, stride HSTR) ----------
#pragma unroll
    for (int it = 0; it < 4; ++it) {
        int idx = it * 256 + t;
        int e = idx >> 4, f = (idx & 15) * 8;
        int a = atom_s[e];
        F8 se = ld8(S_JK + a * 128 + f);
        F8 v0 = ld8(V_JK + a * 384 + f);
        F8 v1 = ld8(V_JK + a * 384 + 128 + f);
        F8 v2 = ld8(V_JK + a * 384 + 256 + f);
        float rx = rdat[e][0], ry = rdat[e][1], rz = rdat[e][2];
        short8 hS, hN, hQ;
#pragma unroll
        for (int j = 0; j < 8; ++j) {
            hS[j] = f2bf(se.v[j]);
            hN[j] = f2bf(sqrtf(v0.v[j] * v0.v[j] + v1.v[j] * v1.v[j] + v2.v[j] * v2.v[j] + 1e-8f));
            hQ[j] = f2bf(v0.v[j] * rx + v1.v[j] * ry + v2.v[j] * rz);
        }
        unsigned short* hr = &LDSu[e * HSTR];
        *(short8*)&hr[f]       = hS;
        *(short8*)&hr[128 + f] = hN;
        *(short8*)&hr[256 + f] = hQ;
    }
    __syncthreads();

    // ---------- mm1: U[64x128] = H[64x384] @ w_s1 ; wave covers 32 cols ----------
    floatx4 acc[4][2];
    const floatx4 zero4 = {0.f, 0.f, 0.f, 0.f};
#pragma unroll
    for (int mi = 0; mi < 4; ++mi) { acc[mi][0] = zero4; acc[mi][1] = zero4; }

#pragma unroll
    for (int kk = 0; kk < 12; ++kk) {
        short8 bfr[2], af[4];
#pragma unroll
        for (int ni = 0; ni < 2; ++ni) {
            int n = wave * 32 + ni * 16 + c16;
            bfr[ni] = *(const short8*)&wt[WS1_O + n * 384 + kk * 32 + q * 8];
        }
#pragma unroll
        for (int mi = 0; mi < 4; ++mi)
            af[mi] = *(const short8*)&LDSu[(mi * 16 + c16) * HSTR + kk * 32 + q * 8];
#pragma unroll
        for (int mi = 0; mi < 4; ++mi)
#pragma unroll
            for (int ni = 0; ni < 2; ++ni)
                acc[mi][ni] = MFMA16(af[mi], bfr[ni], acc[mi][ni]);
    }
    __syncthreads();   // H dead; lnp overlay becomes safe

    // ---------- LayerNorm partials ----------
    float bs1c[2], glc[2], blc[2];
#pragma unroll
    for (int ni = 0; ni < 2; ++ni) {
        int col = wave * 32 + ni * 16 + c16;
        bs1c[ni] = b_s1[col]; glc[ni] = g_ln[col]; blc[ni] = b_ln[col];
    }
#pragma unroll
    for (int mi = 0; mi < 4; ++mi)
#pragma unroll
        for (int r = 0; r < 4; ++r) {
            float s = 0.f, s2 = 0.f;
#pragma unroll
            for (int ni = 0; ni < 2; ++ni) {
                float v = acc[mi][ni][r] + bs1c[ni];
                s += v; s2 += v * v;
            }
#pragma unroll
            for (int d = 1; d < 16; d <<= 1) {
                s  += __shfl_xor(s, d, 64);
                s2 += __shfl_xor(s2, d, 64);
            }
            if (c16 == 0) {
                int row = mi * 16 + q * 4 + r;
                lnp[row * 8 + wave * 2 + 0] = s;
                lnp[row * 8 + wave * 2 + 1] = s2;
            }
        }
    __syncthreads();

    // ---------- LN apply + SiLU -> A2 ; also compute EPI (RBF) ----------
#pragma unroll
    for (int mi = 0; mi < 4; ++mi)
#pragma unroll
        for (int r = 0; r < 4; ++r) {
            int row = mi * 16 + q * 4 + r;
            float su = 0.f, sq2 = 0.f;
#pragma unroll
            for (int w = 0; w < 4; ++w) { su += lnp[row * 8 + w * 2]; sq2 += lnp[row * 8 + w * 2 + 1]; }
            float mu = su * (1.f / 128.f);
            float ms = sq2 * (1.f / 128.f);
            float rstd = rsqrtf(ms - mu * mu + 1e-5f);
#pragma unroll
            for (int ni = 0; ni < 2; ++ni) {
                float v = acc[mi][ni][r] + bs1c[ni];
                float y = (v - mu) * rstd * glc[ni] + blc[ni];
                LDSu[A2_O + row * ASTR + (wave * 32 + ni * 16 + c16)] = (unsigned short)f2bf(silu_f(y));
            }
        }
    {   // EPI: e = t>>2, ng = t&3 (region disjoint from A2/lnp)
        int e = t >> 2, ng = t & 3;
        float dist = rdat[e][3];
        float inv  = invd_s[e];
        short8 pk;
#pragma unroll
        for (int j = 0; j < 8; ++j) {
            float nf = (float)(ng * 8 + j + 1);
            pk[j] = f2bf(__sinf(dist * nf * 0.785398163397448f) * inv);
        }
        *(short8*)&LDSu[EPI_O + e * 40 + ng * 8] = pk;
    }
    __syncthreads();   // A2 + EPI ready

    // ---------- mmf1: F1[64x128] = EPI[64x32] @ w_f1 -> silu -> F1A ----------
    {
        short8 ae[4], be[2];
#pragma unroll
        for (int mi = 0; mi < 4; ++mi)
            ae[mi] = *(const short8*)&LDSu[EPI_O + (mi * 16 + c16) * 40 + q * 8];
#pragma unroll
        for (int ni = 0; ni < 2; ++ni) {
            int n = wave * 32 + ni * 16 + c16;
            be[ni] = *(const short8*)&wt[WF1_O + n * 32 + q * 8];
        }
        floatx4 facc[4][2];
#pragma unroll
        for (int mi = 0; mi < 4; ++mi)
#pragma unroll
            for (int ni = 0; ni < 2; ++ni)
                facc[mi][ni] = MFMA16(ae[mi], be[ni], zero4);
        float bf1c[2];
#pragma unroll
        for (int ni = 0; ni < 2; ++ni) bf1c[ni] = b_f1[wave * 32 + ni * 16 + c16];
#pragma unroll
        for (int mi = 0; mi < 4; ++mi)
#pragma unroll
            for (int r = 0; r < 4; ++r) {
                int row = mi * 16 + q * 4 + r;
#pragma unroll
                for (int ni = 0; ni < 2; ++ni) {
                    float v = facc[mi][ni][r] + bf1c[ni];
                    LDSu[F1_O + row * ASTR + (wave * 32 + ni * 16 + c16)] = (unsigned short)f2bf(silu_f(v));
                }
            }
    }
    __syncthreads();   // F1A ready

    // ---------- mm2: S = A2 @ w_s2 ; mmf2: W = F1A @ w_f2 ; G = W.S -> GA ----------
    {
        floatx4 sacc[4][2], wacc[4][2];
#pragma unroll
        for (int mi = 0; mi < 4; ++mi)
#pragma unroll
            for (int ni = 0; ni < 2; ++ni) { sacc[mi][ni] = zero4; wacc[mi][ni] = zero4; }
#pragma unroll
        for (int kk = 0; kk < 4; ++kk) {
            short8 a2f[4], f1f[4], b2[2], bw[2];
#pragma unroll
            for (int ni = 0; ni < 2; ++ni) {
                int n = wave * 32 + ni * 16 + c16;
                b2[ni] = *(const short8*)&wt[WS2_O + n * 128 + kk * 32 + q * 8];
                bw[ni] = *(const short8*)&wt[WF2_O + n * 128 + kk * 32 + q * 8];
            }
#pragma unroll
            for (int mi = 0; mi < 4; ++mi) {
                a2f[mi] = *(const short8*)&LDSu[A2_O + (mi * 16 + c16) * ASTR + kk * 32 + q * 8];
                f1f[mi] = *(const short8*)&LDSu[F1_O + (mi * 16 + c16) * ASTR + kk * 32 + q * 8];
            }
#pragma unroll
            for (int mi = 0; mi < 4; ++mi)
#pragma unroll
                for (int ni = 0; ni < 2; ++ni) {
                    sacc[mi][ni] = MFMA16(a2f[mi], b2[ni], sacc[mi][ni]);
                    wacc[mi][ni] = MFMA16(f1f[mi], bw[ni], wacc[mi][ni]);
                }
        }
        __syncthreads();   // all reads of A2/F1A complete
        float bs2c[2], bf2c[2];
#pragma unroll
        for (int ni = 0; ni < 2; ++ni) {
            int col = wave * 32 + ni * 16 + c16;
            bs2c[ni] = b_s2[col]; bf2c[ni] = b_f2[col];
        }
#pragma unroll
        for (int mi = 0; mi < 4; ++mi)
#pragma unroll
            for (int r = 0; r < 4; ++r) {
                int row = mi * 16 + q * 4 + r;
#pragma unroll
                for (int ni = 0; ni < 2; ++ni) {
                    float g = (sacc[mi][ni][r] + bs2c[ni]) * (wacc[mi][ni][r] + bf2c[ni]);
                    LDSu[A2_O + row * ASTR + (wave * 32 + ni * 16 + c16)] = (unsigned short)f2bf(g);
                }
            }
    }
    __syncthreads();   // GA ready

    // ---------- head: O1[64x64] = GA @ w_o1 ; m = silu(O1) @ w_o2 ----------
    {
        const int n2 = wave * 16 + c16;     // each wave owns 16 of the 64 head cols
        floatx4 oacc[4];
#pragma unroll
        for (int mi = 0; mi < 4; ++mi) oacc[mi] = zero4;
#pragma unroll
        for (int kk = 0; kk < 4; ++kk) {
            short8 bfr = *(const short8*)&wt[WO1_O + n2 * 128 + kk * 32 + q * 8];
#pragma unroll
            for (int mi = 0; mi < 4; ++mi) {
                short8 af = *(const short8*)&LDSu[A2_O + (mi * 16 + c16) * ASTR + kk * 32 + q * 8];
                oacc[mi] = MFMA16(af, bfr, oacc[mi]);
            }
        }
        float bo1c = b_o1[n2], wo2c = w_o2[n2];
#pragma unroll
        for (int mi = 0; mi < 4; ++mi)
#pragma unroll
            for (int r = 0; r < 4; ++r) {
                float s = silu_f(oacc[mi][r] + bo1c) * wo2c;
#pragma unroll
                for (int d = 1; d < 16; d <<= 1) s += __shfl_xor(s, d, 64);
                if (c16 == 0) mpart[(mi * 16 + q * 4 + r) * 4 + wave] = s;
            }
    }
    __syncthreads();

    // ---------- envelope + scatter-add ----------
    if (t < EPB) {
        float m  = mpart[t * 4 + 0] + mpart[t * 4 + 1] + mpart[t * 4 + 2] + mpart[t * 4 + 3] + b_o2[0];
        float mw = m * env_s[t];
        if (mw != 0.f) unsafeAtomicAdd(&out[probe_s[t]], mw);
    }
}

extern "C" void kernel_launch(void* const* d_in, const int* in_sizes, int n_in,
                              void* d_out, int out_size, void* d_ws, size_t ws_size,
                              hipStream_t stream) {
    const float* diff    = (const float*)d_in[0];
    const float* S_JK    = (const float*)d_in[1];
    const float* V_JK    = (const float*)d_in[2];
    const int*   atom_i  = (const int*)d_in[3];
    const int*   probe_i = (const int*)d_in[4];
    const float* w_s1 = (const float*)d_in[6];
    const float* b_s1 = (const float*)d_in[7];
    const float* g_ln = (const float*)d_in[8];
    const float* b_ln = (const float*)d_in[9];
    const float* w_s2 = (const float*)d_in[10];
    const float* b_s2 = (const float*)d_in[11];
    const float* w_f1 = (const float*)d_in[12];
    const float* b_f1 = (const float*)d_in[13];
    const float* w_f2 = (const float*)d_in[14];
    const float* b_f2 = (const float*)d_in[15];
    const float* w_o1 = (const float*)d_in[16];
    const float* b_o1 = (const float*)d_in[17];
    const float* w_o2 = (const float*)d_in[18];
    const float* b_o2 = (const float*)d_in[19];
    const float* fbias = (const float*)d_in[20];
    float* out = (float*)d_out;
    unsigned short* wt = (unsigned short*)d_ws;   // 188,416 B used

    cfr_prep<<<(NPROBE + 255) / 256, 256, 0, stream>>>(w_s1, w_s2, w_f1, w_f2, w_o1,
                                                       fbias, out, wt);
    cfr_main<<<E_TOTAL / EPB, 256, 0, stream>>>(diff, S_JK, V_JK, atom_i, probe_i, wt,
        b_s1, g_ln, b_ln, b_s2, b_f1, b_f2, b_o1, w_o2, b_o2, out);
}

// Round 3
// 278.679 us; speedup vs baseline: 1.6665x; 1.0346x over previous
//
#include <hip/hip_runtime.h>

#define EPB     64           // edges per block
#define E_TOTAL 262144
#define NPROBE  100000
#define N_ATOMS 20000

// LDS layout (unsigned short indices into LDSu; total 50,176 B + ~2 KB misc)
#define HSTR   392           // H row stride (shorts): 784 B = 16 B * 49
#define ASTR   136           // A2/F1A/GA row stride: 272 B = 16 B * 17
#define A2_O   0             // A2/GA region  [0, 8704) shorts
#define F1_O   8704          // F1A region    [8704, 17408)
#define EPI_O  17408         // EPI region    [17408, 19968), row stride 40 shorts
#define LNP_B  19968         // lnp floats at short-idx 19968, 64*8 floats
#define MPT_B  20992         // mpart floats at short-idx 20992, 64*4 floats
#define LDS_SH 25088         // 64*392 shorts = 50,176 B

// workspace layout (shorts)
#define WS1_O  0             // 128 x 384 (bf16, [n][k])
#define WS2_O  49152         // 128 x 128
#define WF1_O  65536         // 128 x 32
#define WF2_O  69632         // 128 x 128
#define WO1_O  86016         // 64 x 128
#define WT_TOT 94208
#define SB_O   WT_TOT                    // S_bf  [20000][128]
#define NB_O   (SB_O + N_ATOMS * 128)    // n_bf  [20000][128]
#define VB_O   (NB_O + N_ATOMS * 128)    // V_bf  [20000][3][128]
// total = 94208 + 2.56M + 2.56M + 7.68M shorts = ~25.8 MB

typedef __attribute__((ext_vector_type(8))) short          short8;
typedef __attribute__((ext_vector_type(8))) unsigned short ushort8;
typedef __attribute__((ext_vector_type(4))) float          floatx4;

#define MFMA16(a, b, c) __builtin_amdgcn_mfma_f32_16x16x32_bf16((a), (b), (c), 0, 0, 0)

__device__ __forceinline__ short f2bf(float x) {            // RNE (prep only)
    unsigned u = __builtin_bit_cast(unsigned, x);
    u = (u + 0x7FFFu + ((u >> 16) & 1u)) >> 16;
    return (short)(unsigned short)u;
}
// truncating bf16: 1 VALU op per element (or per pair via v_perm)
__device__ __forceinline__ unsigned short bft(float x) {
    return (unsigned short)(__builtin_bit_cast(unsigned, x) >> 16);
}
__device__ __forceinline__ unsigned pk2(float lo, float hi) {   // {bf16(hi),bf16(lo)}
    return __builtin_amdgcn_perm(__builtin_bit_cast(unsigned, hi),
                                 __builtin_bit_cast(unsigned, lo), 0x07060302u);
}
__device__ __forceinline__ float bf2f(unsigned short u) {
    return __builtin_bit_cast(float, ((unsigned)u) << 16);
}

__device__ __forceinline__ float silu_f(float x) { return x / (1.0f + __expf(-x)); }

struct F8 { float v[8]; };
__device__ __forceinline__ F8 ld8(const float* __restrict__ p) {
    F8 r;
    const float4 a = *(const float4*)p;
    const float4 b = *(const float4*)(p + 4);
    r.v[0] = a.x; r.v[1] = a.y; r.v[2] = a.z; r.v[3] = a.w;
    r.v[4] = b.x; r.v[5] = b.y; r.v[6] = b.z; r.v[7] = b.w;
    return r;
}

// prep A: out init + weight transpose->bf16
__global__ void cfr_prep_w(const float* __restrict__ w_s1, const float* __restrict__ w_s2,
                           const float* __restrict__ w_f1, const float* __restrict__ w_f2,
                           const float* __restrict__ w_o1,
                           const float* __restrict__ fb, float* __restrict__ out,
                           unsigned short* __restrict__ wt) {
    int i = blockIdx.x * 256 + threadIdx.x;
    if (i < NPROBE) out[i] = fb[0];
    if (i < WT_TOT) {
        float v;
        if (i < WS2_O)      { int n = i / 384, k = i - n * 384;          v = w_s1[k * 128 + n]; }
        else if (i < WF1_O) { int j = i - WS2_O, n = j >> 7, k = j & 127; v = w_s2[k * 128 + n]; }
        else if (i < WF2_O) { int j = i - WF1_O, n = j >> 5, k = j & 31;  v = w_f1[k * 128 + n]; }
        else if (i < WO1_O) { int j = i - WF2_O, n = j >> 7, k = j & 127; v = w_f2[k * 128 + n]; }
        else                { int j = i - WO1_O, n = j >> 7, k = j & 127; v = w_o1[k * 64 + n]; }
        wt[i] = (unsigned short)f2bf(v);
    }
}

// prep B: per-atom bf16 features: S_bf, n_bf = sqrt(sum_d V^2 + 1e-8), V_bf
__global__ void cfr_prep_atoms(const float* __restrict__ S, const float* __restrict__ V,
                               unsigned short* __restrict__ sb, unsigned short* __restrict__ nb,
                               unsigned short* __restrict__ vb) {
    int i = blockIdx.x * 256 + threadIdx.x;
    if (i >= N_ATOMS * 16) return;
    int a = i >> 4, fb8 = (i & 15) * 8;
    F8 s  = ld8(S + a * 128 + fb8);
    F8 v0 = ld8(V + a * 384 + fb8);
    F8 v1 = ld8(V + a * 384 + 128 + fb8);
    F8 v2 = ld8(V + a * 384 + 256 + fb8);
    ushort8 so, no, w0, w1, w2;
#pragma unroll
    for (int j = 0; j < 8; ++j) {
        so[j] = (unsigned short)f2bf(s.v[j]);
        no[j] = (unsigned short)f2bf(sqrtf(v0.v[j] * v0.v[j] + v1.v[j] * v1.v[j] + v2.v[j] * v2.v[j] + 1e-8f));
        w0[j] = (unsigned short)f2bf(v0.v[j]);
        w1[j] = (unsigned short)f2bf(v1.v[j]);
        w2[j] = (unsigned short)f2bf(v2.v[j]);
    }
    *(ushort8*)&sb[a * 128 + fb8] = so;
    *(ushort8*)&nb[a * 128 + fb8] = no;
    *(ushort8*)&vb[a * 384 + fb8]       = w0;
    *(ushort8*)&vb[a * 384 + 128 + fb8] = w1;
    *(ushort8*)&vb[a * 384 + 256 + fb8] = w2;
}

__global__ __launch_bounds__(256, 3) void cfr_main(
    const float* __restrict__ diff,
    const int* __restrict__ atom_idx, const int* __restrict__ probe_idx,
    const unsigned short* __restrict__ wt,
    const unsigned short* __restrict__ sb, const unsigned short* __restrict__ nb,
    const unsigned short* __restrict__ vb,
    const float* __restrict__ b_s1, const float* __restrict__ g_ln,
    const float* __restrict__ b_ln, const float* __restrict__ b_s2,
    const float* __restrict__ b_f1, const float* __restrict__ b_f2,
    const float* __restrict__ b_o1, const float* __restrict__ w_o2,
    const float* __restrict__ b_o2,
    float* __restrict__ out)
{
    __shared__ __align__(16) unsigned short LDSu[LDS_SH];
    __shared__ float rdat[EPB][4];     // rx, ry, rz, dist
    __shared__ float invd_s[EPB];
    __shared__ float env_s[EPB];
    __shared__ int   probe_s[EPB];
    __shared__ int   atom_s[EPB];

    float* lnp   = (float*)&LDSu[LNP_B];
    float* mpart = (float*)&LDSu[MPT_B];

    const int t    = threadIdx.x;
    const int e0   = blockIdx.x * EPB;
    const int wave = t >> 6;
    const int lane = t & 63;
    const int q    = lane >> 4;
    const int c16  = lane & 15;

    // ---------- phase 0: per-edge scalars ----------
    if (t < EPB) {
        int e = e0 + t;
        float dx = diff[e * 3 + 0], dy = diff[e * 3 + 1], dz = diff[e * 3 + 2];
        float sq   = dx * dx + dy * dy + dz * dz;
        float dist = sqrtf(sq);
        float rinv = 1.0f / sqrtf(sq + 1e-8f);
        rdat[t][0] = dx * rinv; rdat[t][1] = dy * rinv; rdat[t][2] = dz * rinv;
        rdat[t][3] = dist;
        invd_s[t]  = 1.0f / dist;
        float x  = dist * 0.25f;
        float x2 = x * x, x4 = x2 * x2;
        float x5 = x4 * x, x6 = x5 * x, x7 = x6 * x;
        float env = 1.0f - 21.0f * x5 + 35.0f * x6 - 15.0f * x7;
        env_s[t]  = (dist < 4.0f) ? env : 0.0f;
        probe_s[t] = probe_idx[e];
        atom_s[t]  = atom_idx[e];
    }
    __syncthreads();

    // ---------- gather -> H = [S_e | n_e | q_pi] (bf16 pass-through + q_pi dot) ----------
#pragma unroll
    for (int it = 0; it < 4; ++it) {
        int idx = it * 256 + t;
        int e = idx >> 4, f = (idx & 15) * 8;
        int a = atom_s[e];
        ushort8 s8 = *(const ushort8*)&sb[a * 128 + f];
        ushort8 n8 = *(const ushort8*)&nb[a * 128 + f];
        ushort8 v0 = *(const ushort8*)&vb[a * 384 + f];
        ushort8 v1 = *(const ushort8*)&vb[a * 384 + 128 + f];
        ushort8 v2 = *(const ushort8*)&vb[a * 384 + 256 + f];
        float rx = rdat[e][0], ry = rdat[e][1], rz = rdat[e][2];
        unsigned qp[4];
#pragma unroll
        for (int jj = 0; jj < 4; ++jj) {
            float x0 = bf2f(v0[2 * jj]) * rx + bf2f(v1[2 * jj]) * ry + bf2f(v2[2 * jj]) * rz;
            float x1 = bf2f(v0[2 * jj + 1]) * rx + bf2f(v1[2 * jj + 1]) * ry + bf2f(v2[2 * jj + 1]) * rz;
            qp[jj] = pk2(x0, x1);
        }
        unsigned short* hr = &LDSu[e * HSTR];
        *(ushort8*)&hr[f]       = s8;
        *(ushort8*)&hr[128 + f] = n8;
        *(uint4*)&hr[256 + f]   = make_uint4(qp[0], qp[1], qp[2], qp[3]);
    }
    __syncthreads();

    // ---------- mm1: U[64x128] = H[64x384] @ w_s1 ; wave covers 32 cols ----------
    floatx4 acc[4][2];
    const floatx4 zero4 = {0.f, 0.f, 0.f, 0.f};
#pragma unroll
    for (int mi = 0; mi < 4; ++mi) { acc[mi][0] = zero4; acc[mi][1] = zero4; }

#pragma unroll
    for (int kk = 0; kk < 12; ++kk) {
        short8 bfr[2], af[4];
#pragma unroll
        for (int ni = 0; ni < 2; ++ni) {
            int n = wave * 32 + ni * 16 + c16;
            bfr[ni] = *(const short8*)&wt[WS1_O + n * 384 + kk * 32 + q * 8];
        }
#pragma unroll
        for (int mi = 0; mi < 4; ++mi)
            af[mi] = *(const short8*)&LDSu[(mi * 16 + c16) * HSTR + kk * 32 + q * 8];
#pragma unroll
        for (int mi = 0; mi < 4; ++mi)
#pragma unroll
            for (int ni = 0; ni < 2; ++ni)
                acc[mi][ni] = MFMA16(af[mi], bfr[ni], acc[mi][ni]);
    }
    __syncthreads();   // H dead; overlays safe

    // ---------- LayerNorm partials ----------
    float bs1c[2], glc[2], blc[2];
#pragma unroll
    for (int ni = 0; ni < 2; ++ni) {
        int col = wave * 32 + ni * 16 + c16;
        bs1c[ni] = b_s1[col]; glc[ni] = g_ln[col]; blc[ni] = b_ln[col];
    }
#pragma unroll
    for (int mi = 0; mi < 4; ++mi)
#pragma unroll
        for (int r = 0; r < 4; ++r) {
            float s = 0.f, s2 = 0.f;
#pragma unroll
            for (int ni = 0; ni < 2; ++ni) {
                float v = acc[mi][ni][r] + bs1c[ni];
                s += v; s2 += v * v;
            }
#pragma unroll
            for (int d = 1; d < 16; d <<= 1) {
                s  += __shfl_xor(s, d, 64);
                s2 += __shfl_xor(s2, d, 64);
            }
            if (c16 == 0) {
                int row = mi * 16 + q * 4 + r;
                lnp[row * 8 + wave * 2 + 0] = s;
                lnp[row * 8 + wave * 2 + 1] = s2;
            }
        }
    __syncthreads();

    // ---------- LN apply + SiLU -> A2 ; EPI (RBF) ----------
#pragma unroll
    for (int mi = 0; mi < 4; ++mi)
#pragma unroll
        for (int r = 0; r < 4; ++r) {
            int row = mi * 16 + q * 4 + r;
            float su = 0.f, sq2 = 0.f;
#pragma unroll
            for (int w = 0; w < 4; ++w) { su += lnp[row * 8 + w * 2]; sq2 += lnp[row * 8 + w * 2 + 1]; }
            float mu = su * (1.f / 128.f);
            float ms = sq2 * (1.f / 128.f);
            float rstd = rsqrtf(ms - mu * mu + 1e-5f);
#pragma unroll
            for (int ni = 0; ni < 2; ++ni) {
                float v = acc[mi][ni][r] + bs1c[ni];
                float y = (v - mu) * rstd * glc[ni] + blc[ni];
                LDSu[A2_O + row * ASTR + (wave * 32 + ni * 16 + c16)] = bft(silu_f(y));
            }
        }
    {   // EPI: e = t>>2, ng = t&3
        int e = t >> 2, ng = t & 3;
        float dist = rdat[e][3];
        float inv  = invd_s[e];
        float sv[8];
#pragma unroll
        for (int j = 0; j < 8; ++j) {
            float nf = (float)(ng * 8 + j + 1);
            sv[j] = __sinf(dist * nf * 0.785398163397448f) * inv;
        }
        *(uint4*)&LDSu[EPI_O + e * 40 + ng * 8] =
            make_uint4(pk2(sv[0], sv[1]), pk2(sv[2], sv[3]), pk2(sv[4], sv[5]), pk2(sv[6], sv[7]));
    }
    __syncthreads();   // A2 + EPI ready

    // ---------- mmf1: F1[64x128] = EPI[64x32] @ w_f1 -> silu -> F1A ----------
    {
        short8 ae[4], be[2];
#pragma unroll
        for (int mi = 0; mi < 4; ++mi)
            ae[mi] = *(const short8*)&LDSu[EPI_O + (mi * 16 + c16) * 40 + q * 8];
#pragma unroll
        for (int ni = 0; ni < 2; ++ni) {
            int n = wave * 32 + ni * 16 + c16;
            be[ni] = *(const short8*)&wt[WF1_O + n * 32 + q * 8];
        }
        floatx4 facc[4][2];
#pragma unroll
        for (int mi = 0; mi < 4; ++mi)
#pragma unroll
            for (int ni = 0; ni < 2; ++ni)
                facc[mi][ni] = MFMA16(ae[mi], be[ni], zero4);
        float bf1c[2];
#pragma unroll
        for (int ni = 0; ni < 2; ++ni) bf1c[ni] = b_f1[wave * 32 + ni * 16 + c16];
#pragma unroll
        for (int mi = 0; mi < 4; ++mi)
#pragma unroll
            for (int r = 0; r < 4; ++r) {
                int row = mi * 16 + q * 4 + r;
#pragma unroll
                for (int ni = 0; ni < 2; ++ni) {
                    float v = facc[mi][ni][r] + bf1c[ni];
                    LDSu[F1_O + row * ASTR + (wave * 32 + ni * 16 + c16)] = bft(silu_f(v));
                }
            }
    }
    __syncthreads();   // F1A ready

    // ---------- mm2: S = A2 @ w_s2 ; mmf2: W = F1A @ w_f2 ; G = W.S -> GA ----------
    {
        floatx4 sacc[4][2], wacc[4][2];
#pragma unroll
        for (int mi = 0; mi < 4; ++mi)
#pragma unroll
            for (int ni = 0; ni < 2; ++ni) { sacc[mi][ni] = zero4; wacc[mi][ni] = zero4; }
#pragma unroll
        for (int kk = 0; kk < 4; ++kk) {
            short8 a2f[4], f1f[4], b2[2], bw[2];
#pragma unroll
            for (int ni = 0; ni < 2; ++ni) {
                int n = wave * 32 + ni * 16 + c16;
                b2[ni] = *(const short8*)&wt[WS2_O + n * 128 + kk * 32 + q * 8];
                bw[ni] = *(const short8*)&wt[WF2_O + n * 128 + kk * 32 + q * 8];
            }
#pragma unroll
            for (int mi = 0; mi < 4; ++mi) {
                a2f[mi] = *(const short8*)&LDSu[A2_O + (mi * 16 + c16) * ASTR + kk * 32 + q * 8];
                f1f[mi] = *(const short8*)&LDSu[F1_O + (mi * 16 + c16) * ASTR + kk * 32 + q * 8];
            }
#pragma unroll
            for (int mi = 0; mi < 4; ++mi)
#pragma unroll
                for (int ni = 0; ni < 2; ++ni) {
                    sacc[mi][ni] = MFMA16(a2f[mi], b2[ni], sacc[mi][ni]);
                    wacc[mi][ni] = MFMA16(f1f[mi], bw[ni], wacc[mi][ni]);
                }
        }
        __syncthreads();   // all reads of A2/F1A complete
        float bs2c[2], bf2c[2];
#pragma unroll
        for (int ni = 0; ni < 2; ++ni) {
            int col = wave * 32 + ni * 16 + c16;
            bs2c[ni] = b_s2[col]; bf2c[ni] = b_f2[col];
        }
#pragma unroll
        for (int mi = 0; mi < 4; ++mi)
#pragma unroll
            for (int r = 0; r < 4; ++r) {
                int row = mi * 16 + q * 4 + r;
#pragma unroll
                for (int ni = 0; ni < 2; ++ni) {
                    float g = (sacc[mi][ni][r] + bs2c[ni]) * (wacc[mi][ni][r] + bf2c[ni]);
                    LDSu[A2_O + row * ASTR + (wave * 32 + ni * 16 + c16)] = bft(g);
                }
            }
    }
    __syncthreads();   // GA ready

    // ---------- head: O1[64x64] = GA @ w_o1 ; m = silu(O1) @ w_o2 ----------
    {
        const int n2 = wave * 16 + c16;
        floatx4 oacc[4];
#pragma unroll
        for (int mi = 0; mi < 4; ++mi) oacc[mi] = zero4;
#pragma unroll
        for (int kk = 0; kk < 4; ++kk) {
            short8 bfr = *(const short8*)&wt[WO1_O + n2 * 128 + kk * 32 + q * 8];
#pragma unroll
            for (int mi = 0; mi < 4; ++mi) {
                short8 af = *(const short8*)&LDSu[A2_O + (mi * 16 + c16) * ASTR + kk * 32 + q * 8];
                oacc[mi] = MFMA16(af, bfr, oacc[mi]);
            }
        }
        float bo1c = b_o1[n2], wo2c = w_o2[n2];
#pragma unroll
        for (int mi = 0; mi < 4; ++mi)
#pragma unroll
            for (int r = 0; r < 4; ++r) {
                float s = silu_f(oacc[mi][r] + bo1c) * wo2c;
#pragma unroll
                for (int d = 1; d < 16; d <<= 1) s += __shfl_xor(s, d, 64);
                if (c16 == 0) mpart[(mi * 16 + q * 4 + r) * 4 + wave] = s;
            }
    }
    __syncthreads();

    // ---------- envelope + scatter-add ----------
    if (t < EPB) {
        float m  = mpart[t * 4 + 0] + mpart[t * 4 + 1] + mpart[t * 4 + 2] + mpart[t * 4 + 3] + b_o2[0];
        float mw = m * env_s[t];
        if (mw != 0.f) unsafeAtomicAdd(&out[probe_s[t]], mw);
    }
}

extern "C" void kernel_launch(void* const* d_in, const int* in_sizes, int n_in,
                              void* d_out, int out_size, void* d_ws, size_t ws_size,
                              hipStream_t stream) {
    const float* diff    = (const float*)d_in[0];
    const float* S_JK    = (const float*)d_in[1];
    const float* V_JK    = (const float*)d_in[2];
    const int*   atom_i  = (const int*)d_in[3];
    const int*   probe_i = (const int*)d_in[4];
    const float* w_s1 = (const float*)d_in[6];
    const float* b_s1 = (const float*)d_in[7];
    const float* g_ln = (const float*)d_in[8];
    const float* b_ln = (const float*)d_in[9];
    const float* w_s2 = (const float*)d_in[10];
    const float* b_s2 = (const float*)d_in[11];
    const float* w_f1 = (const float*)d_in[12];
    const float* b_f1 = (const float*)d_in[13];
    const float* w_f2 = (const float*)d_in[14];
    const float* b_f2 = (const float*)d_in[15];
    const float* w_o1 = (const float*)d_in[16];
    const float* b_o1 = (const float*)d_in[17];
    const float* w_o2 = (const float*)d_in[18];
    const float* b_o2 = (const float*)d_in[19];
    const float* fbias = (const float*)d_in[20];
    float* out = (float*)d_out;

    unsigned short* wt = (unsigned short*)d_ws;
    unsigned short* sbp = wt + SB_O;
    unsigned short* nbp = wt + NB_O;
    unsigned short* vbp = wt + VB_O;

    cfr_prep_w<<<(NPROBE + 255) / 256, 256, 0, stream>>>(w_s1, w_s2, w_f1, w_f2, w_o1,
                                                         fbias, out, wt);
    cfr_prep_atoms<<<(N_ATOMS * 16 + 255) / 256, 256, 0, stream>>>(S_JK, V_JK, sbp, nbp, vbp);
    cfr_main<<<E_TOTAL / EPB, 256, 0, stream>>>(diff, atom_i, probe_i, wt, sbp, nbp, vbp,
        b_s1, g_ln, b_ln, b_s2, b_f1, b_f2, b_o1, w_o2, b_o2, out);
}

// Round 4
// 240.976 us; speedup vs baseline: 1.9273x; 1.1565x over previous
//
#include <hip/hip_runtime.h>

#define EPB     64
#define E_TOTAL 262144
#define NPROBE  100000
#define N_ATOMS 20000

// LDS layout (main), unsigned short indices; total 39,936 B
#define ASTR   136           // A2/F1A row stride: 272 B = 16 B * 17 -> 2-way (free) banks
#define A2_O   0             // A2 / G region [0, 8704)
#define F1_O   8704          // F1A region    [8704, 17408)
#define EPI_O  17408         // EPI 64 x 40 shorts; overlaid by mpart floats in head phase
#define LDS_SH 19968         // 39,936 B -> 4 blocks/CU

// workspace layout (shorts)
#define WS1_O  0             // w_s1^T bf16: 128 x 384 ([n][k])
#define WS2_O  49152         // 128 x 128
#define WF1_O  65536         // 128 x 32
#define WF2_O  69632         // 128 x 128
#define WO1_O  86016         // 64 x 128
#define WT_TOT 94208
#define PQ_O   WT_TOT        // PQ[a][512] bf16: [P | Q0 | Q1 | Q2], 20.5 MB

typedef __attribute__((ext_vector_type(8))) short          short8;
typedef __attribute__((ext_vector_type(8))) unsigned short ushort8;
typedef __attribute__((ext_vector_type(4))) float          floatx4;

#define MFMA16(a, b, c) __builtin_amdgcn_mfma_f32_16x16x32_bf16((a), (b), (c), 0, 0, 0)

__device__ __forceinline__ short f2bf(float x) {            // RNE (prep only)
    unsigned u = __builtin_bit_cast(unsigned, x);
    u = (u + 0x7FFFu + ((u >> 16) & 1u)) >> 16;
    return (short)(unsigned short)u;
}
__device__ __forceinline__ unsigned pk2(float lo, float hi) {   // {bf16(hi)|bf16(lo)} trunc
    return __builtin_amdgcn_perm(__builtin_bit_cast(unsigned, hi),
                                 __builtin_bit_cast(unsigned, lo), 0x07060302u);
}
__device__ __forceinline__ float bf2f(unsigned short u) {
    return __builtin_bit_cast(float, ((unsigned)u) << 16);
}
__device__ __forceinline__ float silu_f(float x) { return x / (1.0f + __expf(-x)); }

struct F8 { float v[8]; };
__device__ __forceinline__ F8 ld8(const float* __restrict__ p) {
    F8 r;
    const float4 a = *(const float4*)p;
    const float4 b = *(const float4*)(p + 4);
    r.v[0] = a.x; r.v[1] = a.y; r.v[2] = a.z; r.v[3] = a.w;
    r.v[4] = b.x; r.v[5] = b.y; r.v[6] = b.z; r.v[7] = b.w;
    return r;
}

// prep 1: out init + weight transpose -> bf16 [n][k]
__global__ void cfr_prep_w(const float* __restrict__ w_s1, const float* __restrict__ w_s2,
                           const float* __restrict__ w_f1, const float* __restrict__ w_f2,
                           const float* __restrict__ w_o1,
                           const float* __restrict__ fb, float* __restrict__ out,
                           unsigned short* __restrict__ wt) {
    int i = blockIdx.x * 256 + threadIdx.x;
    if (i < NPROBE) out[i] = fb[0];
    if (i < WT_TOT) {
        float v;
        if (i < WS2_O)      { int n = i / 384, k = i - n * 384;          v = w_s1[k * 128 + n]; }
        else if (i < WF1_O) { int j = i - WS2_O, n = j >> 7, k = j & 127; v = w_s2[k * 128 + n]; }
        else if (i < WF2_O) { int j = i - WF1_O, n = j >> 5, k = j & 31;  v = w_f1[k * 128 + n]; }
        else if (i < WO1_O) { int j = i - WF2_O, n = j >> 7, k = j & 127; v = w_f2[k * 128 + n]; }
        else                { int j = i - WO1_O, n = j >> 7, k = j & 127; v = w_o1[k * 64 + n]; }
        wt[i] = (unsigned short)f2bf(v);
    }
}

// prep 2: per-atom P = [S|n]@w_s1[0:256] + b_s1 and Q_d = V_d@w_s1[256:384], bf16.
// One block = 64 atoms; MFMA with A staged in LDS, B from wt (bf16-transposed w_s1).
__global__ __launch_bounds__(256, 1) void cfr_prep_pq(
    const float* __restrict__ S, const float* __restrict__ V,
    const float* __restrict__ b_s1,
    const unsigned short* __restrict__ wt, unsigned short* __restrict__ pq)
{
    __shared__ __align__(16) unsigned short bufH[64 * 264];   // [S|n], stride 264
    __shared__ __align__(16) unsigned short bufV[192 * 136];  // rows (d*64 + a_local)

    const int t    = threadIdx.x;
    const int a0   = blockIdx.x * 64;
    const int wave = t >> 6;
    const int lane = t & 63;
    const int q    = lane >> 4;
    const int c16  = lane & 15;

    // stage
#pragma unroll
    for (int it = 0; it < 4; ++it) {
        int idx = it * 256 + t;
        int al = idx >> 4, f8 = (idx & 15) * 8;
        int a = a0 + al;
        ushort8 sS, sN, s0, s1, s2;
        if (a < N_ATOMS) {
            F8 s  = ld8(S + a * 128 + f8);
            F8 v0 = ld8(V + a * 384 + f8);
            F8 v1 = ld8(V + a * 384 + 128 + f8);
            F8 v2 = ld8(V + a * 384 + 256 + f8);
#pragma unroll
            for (int j = 0; j < 8; ++j) {
                sS[j] = (unsigned short)f2bf(s.v[j]);
                sN[j] = (unsigned short)f2bf(sqrtf(v0.v[j]*v0.v[j] + v1.v[j]*v1.v[j] + v2.v[j]*v2.v[j] + 1e-8f));
                s0[j] = (unsigned short)f2bf(v0.v[j]);
                s1[j] = (unsigned short)f2bf(v1.v[j]);
                s2[j] = (unsigned short)f2bf(v2.v[j]);
            }
        } else {
#pragma unroll
            for (int j = 0; j < 8; ++j) { sS[j]=0; sN[j]=0; s0[j]=0; s1[j]=0; s2[j]=0; }
        }
        *(ushort8*)&bufH[al * 264 + f8]        = sS;
        *(ushort8*)&bufH[al * 264 + 128 + f8]  = sN;
        *(ushort8*)&bufV[(al) * 136 + f8]       = s0;
        *(ushort8*)&bufV[(64 + al) * 136 + f8]  = s1;
        *(ushort8*)&bufV[(128 + al) * 136 + f8] = s2;
    }
    __syncthreads();

    const floatx4 zero4 = {0.f, 0.f, 0.f, 0.f};
    float bs1c[2];
#pragma unroll
    for (int ni = 0; ni < 2; ++ni) bs1c[ni] = b_s1[wave * 32 + ni * 16 + c16];

    // P = [S|n] @ w_s1[0:256]
    {
        floatx4 pacc[4][2];
#pragma unroll
        for (int mi = 0; mi < 4; ++mi) { pacc[mi][0] = zero4; pacc[mi][1] = zero4; }
#pragma unroll
        for (int kk = 0; kk < 8; ++kk) {
            short8 bfr[2], af[4];
#pragma unroll
            for (int ni = 0; ni < 2; ++ni) {
                int n = wave * 32 + ni * 16 + c16;
                bfr[ni] = *(const short8*)&wt[WS1_O + n * 384 + kk * 32 + q * 8];
            }
#pragma unroll
            for (int mi = 0; mi < 4; ++mi)
                af[mi] = *(const short8*)&bufH[(mi * 16 + c16) * 264 + kk * 32 + q * 8];
#pragma unroll
            for (int mi = 0; mi < 4; ++mi)
#pragma unroll
                for (int ni = 0; ni < 2; ++ni)
                    pacc[mi][ni] = MFMA16(af[mi], bfr[ni], pacc[mi][ni]);
        }
#pragma unroll
        for (int mi = 0; mi < 4; ++mi)
#pragma unroll
            for (int r = 0; r < 4; ++r) {
                int a = a0 + mi * 16 + q * 4 + r;
                if (a < N_ATOMS)
#pragma unroll
                    for (int ni = 0; ni < 2; ++ni) {
                        int col = wave * 32 + ni * 16 + c16;
                        pq[a * 512 + col] = (unsigned short)f2bf(pacc[mi][ni][r] + bs1c[ni]);
                    }
            }
    }

    // Q_d = V_d @ w_s1[256:384] (B frags hoisted)
    short8 bq[4][2];
#pragma unroll
    for (int kk = 0; kk < 4; ++kk)
#pragma unroll
        for (int ni = 0; ni < 2; ++ni) {
            int n = wave * 32 + ni * 16 + c16;
            bq[kk][ni] = *(const short8*)&wt[WS1_O + n * 384 + 256 + kk * 32 + q * 8];
        }
#pragma unroll
    for (int d = 0; d < 3; ++d) {
        floatx4 qacc[4][2];
#pragma unroll
        for (int mi = 0; mi < 4; ++mi) { qacc[mi][0] = zero4; qacc[mi][1] = zero4; }
#pragma unroll
        for (int kk = 0; kk < 4; ++kk) {
            short8 af[4];
#pragma unroll
            for (int mi = 0; mi < 4; ++mi)
                af[mi] = *(const short8*)&bufV[(d * 64 + mi * 16 + c16) * 136 + kk * 32 + q * 8];
#pragma unroll
            for (int mi = 0; mi < 4; ++mi)
#pragma unroll
                for (int ni = 0; ni < 2; ++ni)
                    qacc[mi][ni] = MFMA16(af[mi], bq[kk][ni], qacc[mi][ni]);
        }
#pragma unroll
        for (int mi = 0; mi < 4; ++mi)
#pragma unroll
            for (int r = 0; r < 4; ++r) {
                int a = a0 + mi * 16 + q * 4 + r;
                if (a < N_ATOMS)
#pragma unroll
                    for (int ni = 0; ni < 2; ++ni) {
                        int col = wave * 32 + ni * 16 + c16;
                        pq[a * 512 + (1 + d) * 128 + col] = (unsigned short)f2bf(qacc[mi][ni][r]);
                    }
            }
    }
}

__global__ __launch_bounds__(256, 4) void cfr_main(
    const float* __restrict__ diff,
    const int* __restrict__ atom_idx, const int* __restrict__ probe_idx,
    const unsigned short* __restrict__ wt, const unsigned short* __restrict__ pq,
    const float* __restrict__ g_ln, const float* __restrict__ b_ln,
    const float* __restrict__ b_s2, const float* __restrict__ b_f1,
    const float* __restrict__ b_f2, const float* __restrict__ b_o1,
    const float* __restrict__ w_o2, const float* __restrict__ b_o2,
    float* __restrict__ out)
{
    __shared__ __align__(16) unsigned short LDSu[LDS_SH];
    float* mpart = (float*)&LDSu[EPI_O];   // overlays EPI after mmf1

    const int t    = threadIdx.x;
    const int e0   = blockIdx.x * EPB;
    const int wave = t >> 6;
    const int lane = t & 63;
    const int q    = lane >> 4;
    const int c16  = lane & 15;
    const floatx4 zero4 = {0.f, 0.f, 0.f, 0.f};

    // ---------- phase 1: U = P + r.Q -> LN -> SiLU -> A2 ; EPI ----------
    {
        const int el = t >> 2;             // local edge 0..63
        const int c0 = (t & 3) * 32;       // this thread's 32-col chunk
        const int eg = e0 + el;
        const int a  = atom_idx[eg];
        float dx = diff[eg * 3 + 0], dy = diff[eg * 3 + 1], dz = diff[eg * 3 + 2];
        float sq   = dx * dx + dy * dy + dz * dz;
        float dist = sqrtf(sq);
        float rinv = rsqrtf(sq + 1e-8f);
        float rx = dx * rinv, ry = dy * rinv, rz = dz * rinv;

        const ushort8* pqr = (const ushort8*)(pq + a * 512 + c0);
        float u[32];
#pragma unroll
        for (int g = 0; g < 4; ++g) {
            ushort8 v = pqr[g];            // P
#pragma unroll
            for (int j = 0; j < 8; ++j) u[g * 8 + j] = bf2f(v[j]);
        }
#pragma unroll
        for (int g = 0; g < 4; ++g) {
            ushort8 v = pqr[16 + g];       // Q0 (offset 128 shorts = 16 ushort8)
#pragma unroll
            for (int j = 0; j < 8; ++j) u[g * 8 + j] = fmaf(bf2f(v[j]), rx, u[g * 8 + j]);
        }
#pragma unroll
        for (int g = 0; g < 4; ++g) {
            ushort8 v = pqr[32 + g];       // Q1
#pragma unroll
            for (int j = 0; j < 8; ++j) u[g * 8 + j] = fmaf(bf2f(v[j]), ry, u[g * 8 + j]);
        }
#pragma unroll
        for (int g = 0; g < 4; ++g) {
            ushort8 v = pqr[48 + g];       // Q2
#pragma unroll
            for (int j = 0; j < 8; ++j) u[g * 8 + j] = fmaf(bf2f(v[j]), rz, u[g * 8 + j]);
        }
        // LayerNorm stats: quad-local (threads t^1, t^2 share this edge)
        float s = 0.f, s2 = 0.f;
#pragma unroll
        for (int j = 0; j < 32; ++j) { s += u[j]; s2 = fmaf(u[j], u[j], s2); }
        s  += __shfl_xor(s, 1);  s  += __shfl_xor(s, 2);
        s2 += __shfl_xor(s2, 1); s2 += __shfl_xor(s2, 2);
        float mu = s * (1.f / 128.f);
        float rstd = rsqrtf(s2 * (1.f / 128.f) - mu * mu + 1e-5f);
        // LN apply + SiLU -> bf16 pack
        const float4* gp = (const float4*)(g_ln + c0);
        const float4* bp = (const float4*)(b_ln + c0);
        unsigned pko[16];
#pragma unroll
        for (int g4 = 0; g4 < 8; ++g4) {
            float4 gg = gp[g4], bb = bp[g4];
            float y0 = silu_f((u[g4 * 4 + 0] - mu) * rstd * gg.x + bb.x);
            float y1 = silu_f((u[g4 * 4 + 1] - mu) * rstd * gg.y + bb.y);
            float y2 = silu_f((u[g4 * 4 + 2] - mu) * rstd * gg.z + bb.z);
            float y3 = silu_f((u[g4 * 4 + 3] - mu) * rstd * gg.w + bb.w);
            pko[g4 * 2 + 0] = pk2(y0, y1);
            pko[g4 * 2 + 1] = pk2(y2, y3);
        }
        uint4* dst = (uint4*)&LDSu[A2_O + el * ASTR + c0];
        dst[0] = make_uint4(pko[0], pko[1], pko[2], pko[3]);
        dst[1] = make_uint4(pko[4], pko[5], pko[6], pko[7]);
        dst[2] = make_uint4(pko[8], pko[9], pko[10], pko[11]);
        dst[3] = make_uint4(pko[12], pko[13], pko[14], pko[15]);
        // EPI: 8 RBF cols per thread
        float inv = 1.0f / dist;
        float sv[8];
#pragma unroll
        for (int j = 0; j < 8; ++j) {
            float nf = (float)((t & 3) * 8 + j + 1);
            sv[j] = __sinf(dist * nf * 0.785398163397448f) * inv;
        }
        *(uint4*)&LDSu[EPI_O + el * 40 + (t & 3) * 8] =
            make_uint4(pk2(sv[0], sv[1]), pk2(sv[2], sv[3]), pk2(sv[4], sv[5]), pk2(sv[6], sv[7]));
    }
    __syncthreads();   // A2 + EPI ready

    // ---------- mmf1: F1 = EPI[64x32] @ w_f1 -> silu -> F1A ----------
    {
        short8 ae[4], be[2];
#pragma unroll
        for (int mi = 0; mi < 4; ++mi)
            ae[mi] = *(const short8*)&LDSu[EPI_O + (mi * 16 + c16) * 40 + q * 8];
#pragma unroll
        for (int ni = 0; ni < 2; ++ni) {
            int n = wave * 32 + ni * 16 + c16;
            be[ni] = *(const short8*)&wt[WF1_O + n * 32 + q * 8];
        }
        floatx4 facc[4][2];
#pragma unroll
        for (int mi = 0; mi < 4; ++mi)
#pragma unroll
            for (int ni = 0; ni < 2; ++ni)
                facc[mi][ni] = MFMA16(ae[mi], be[ni], zero4);
        float bf1c[2];
#pragma unroll
        for (int ni = 0; ni < 2; ++ni) bf1c[ni] = b_f1[wave * 32 + ni * 16 + c16];
#pragma unroll
        for (int mi = 0; mi < 4; ++mi)
#pragma unroll
            for (int r = 0; r < 4; ++r) {
                int row = mi * 16 + q * 4 + r;
#pragma unroll
                for (int ni = 0; ni < 2; ++ni) {
                    float v = facc[mi][ni][r] + bf1c[ni];
                    LDSu[F1_O + row * ASTR + (wave * 32 + ni * 16 + c16)] =
                        (unsigned short)(__builtin_bit_cast(unsigned, silu_f(v)) >> 16);
                }
            }
    }
    __syncthreads();   // F1A ready (EPI now dead)

    // ---------- mm2: S = A2 @ w_s2 ; mmf2: W = F1A @ w_f2 ; G = S.W -> A2 region ----------
    {
        floatx4 sacc[4][2], wacc[4][2];
#pragma unroll
        for (int mi = 0; mi < 4; ++mi)
#pragma unroll
            for (int ni = 0; ni < 2; ++ni) { sacc[mi][ni] = zero4; wacc[mi][ni] = zero4; }
#pragma unroll
        for (int kk = 0; kk < 4; ++kk) {
            short8 a2f[4], f1f[4], b2[2], bw[2];
#pragma unroll
            for (int ni = 0; ni < 2; ++ni) {
                int n = wave * 32 + ni * 16 + c16;
                b2[ni] = *(const short8*)&wt[WS2_O + n * 128 + kk * 32 + q * 8];
                bw[ni] = *(const short8*)&wt[WF2_O + n * 128 + kk * 32 + q * 8];
            }
#pragma unroll
            for (int mi = 0; mi < 4; ++mi) {
                a2f[mi] = *(const short8*)&LDSu[A2_O + (mi * 16 + c16) * ASTR + kk * 32 + q * 8];
                f1f[mi] = *(const short8*)&LDSu[F1_O + (mi * 16 + c16) * ASTR + kk * 32 + q * 8];
            }
#pragma unroll
            for (int mi = 0; mi < 4; ++mi)
#pragma unroll
                for (int ni = 0; ni < 2; ++ni) {
                    sacc[mi][ni] = MFMA16(a2f[mi], b2[ni], sacc[mi][ni]);
                    wacc[mi][ni] = MFMA16(f1f[mi], bw[ni], wacc[mi][ni]);
                }
        }
        __syncthreads();   // all reads of A2/F1A complete
        float bs2c[2], bf2c[2];
#pragma unroll
        for (int ni = 0; ni < 2; ++ni) {
            int col = wave * 32 + ni * 16 + c16;
            bs2c[ni] = b_s2[col]; bf2c[ni] = b_f2[col];
        }
#pragma unroll
        for (int mi = 0; mi < 4; ++mi)
#pragma unroll
            for (int r = 0; r < 4; ++r) {
                int row = mi * 16 + q * 4 + r;
#pragma unroll
                for (int ni = 0; ni < 2; ++ni) {
                    float g = (sacc[mi][ni][r] + bs2c[ni]) * (wacc[mi][ni][r] + bf2c[ni]);
                    LDSu[A2_O + row * ASTR + (wave * 32 + ni * 16 + c16)] =
                        (unsigned short)(__builtin_bit_cast(unsigned, g) >> 16);
                }
            }
    }
    __syncthreads();   // G ready

    // ---------- head: O1 = G @ w_o1 ; m = silu(O1) @ w_o2 ----------
    {
        const int n2 = wave * 16 + c16;
        floatx4 oacc[4];
#pragma unroll
        for (int mi = 0; mi < 4; ++mi) oacc[mi] = zero4;
#pragma unroll
        for (int kk = 0; kk < 4; ++kk) {
            short8 bfr = *(const short8*)&wt[WO1_O + n2 * 128 + kk * 32 + q * 8];
#pragma unroll
            for (int mi = 0; mi < 4; ++mi) {
                short8 af = *(const short8*)&LDSu[A2_O + (mi * 16 + c16) * ASTR + kk * 32 + q * 8];
                oacc[mi] = MFMA16(af, bfr, oacc[mi]);
            }
        }
        float bo1c = b_o1[n2], wo2c = w_o2[n2];
#pragma unroll
        for (int mi = 0; mi < 4; ++mi)
#pragma unroll
            for (int r = 0; r < 4; ++r) {
                float s = silu_f(oacc[mi][r] + bo1c) * wo2c;
#pragma unroll
                for (int d = 1; d < 16; d <<= 1) s += __shfl_xor(s, d, 64);
                if (c16 == 0) mpart[(mi * 16 + q * 4 + r) * 4 + wave] = s;
            }
    }
    __syncthreads();

    // ---------- envelope + scatter-add ----------
    if (t < EPB) {
        int eg = e0 + t;
        float m = mpart[t * 4 + 0] + mpart[t * 4 + 1] + mpart[t * 4 + 2] + mpart[t * 4 + 3] + b_o2[0];
        float dx = diff[eg * 3 + 0], dy = diff[eg * 3 + 1], dz = diff[eg * 3 + 2];
        float dist = sqrtf(dx * dx + dy * dy + dz * dz);
        float x  = dist * 0.25f;
        float x2 = x * x, x4 = x2 * x2;
        float x5 = x4 * x, x6 = x5 * x, x7 = x6 * x;
        float env = 1.0f - 21.0f * x5 + 35.0f * x6 - 15.0f * x7;
        env = (dist < 4.0f) ? env : 0.0f;
        float mw = m * env;
        if (mw != 0.f) unsafeAtomicAdd(&out[probe_idx[eg]], mw);
    }
}

extern "C" void kernel_launch(void* const* d_in, const int* in_sizes, int n_in,
                              void* d_out, int out_size, void* d_ws, size_t ws_size,
                              hipStream_t stream) {
    const float* diff    = (const float*)d_in[0];
    const float* S_JK    = (const float*)d_in[1];
    const float* V_JK    = (const float*)d_in[2];
    const int*   atom_i  = (const int*)d_in[3];
    const int*   probe_i = (const int*)d_in[4];
    const float* w_s1 = (const float*)d_in[6];
    const float* b_s1 = (const float*)d_in[7];
    const float* g_ln = (const float*)d_in[8];
    const float* b_ln = (const float*)d_in[9];
    const float* w_s2 = (const float*)d_in[10];
    const float* b_s2 = (const float*)d_in[11];
    const float* w_f1 = (const float*)d_in[12];
    const float* b_f1 = (const float*)d_in[13];
    const float* w_f2 = (const float*)d_in[14];
    const float* b_f2 = (const float*)d_in[15];
    const float* w_o1 = (const float*)d_in[16];
    const float* b_o1 = (const float*)d_in[17];
    const float* w_o2 = (const float*)d_in[18];
    const float* b_o2 = (const float*)d_in[19];
    const float* fbias = (const float*)d_in[20];
    float* out = (float*)d_out;

    unsigned short* wt = (unsigned short*)d_ws;
    unsigned short* pqp = wt + PQ_O;   // 20.5 MB

    cfr_prep_w<<<(NPROBE + 255) / 256, 256, 0, stream>>>(w_s1, w_s2, w_f1, w_f2, w_o1,
                                                         fbias, out, wt);
    cfr_prep_pq<<<(N_ATOMS + 63) / 64, 256, 0, stream>>>(S_JK, V_JK, b_s1, wt, pqp);
    cfr_main<<<E_TOTAL / EPB, 256, 0, stream>>>(diff, atom_i, probe_i, wt, pqp,
        g_ln, b_ln, b_s2, b_f1, b_f2, b_o1, w_o2, b_o2, out);
}